// Round 15
// baseline (20800.800 us; speedup 1.0000x reference)
//
#include <hip/hip_runtime.h>
#include <hip/hip_bf16.h>
#include <math.h>

#define BATCH 128
#define NN 512
#define DD 128
#define D3 384
#define NEGV (-1.0e9f)
#define NEGINF (-1.0e30f)

// workspace layout (floats): [flags: 256 ints][comm: 128*304][proj][E12][fixedc][q0]
#define COMM_STRIDE 304
#define COMM_F (256 + BATCH * COMM_STRIDE)

// ---- k_fixed: graph mean -> fixed ctx; also q0 = fixed + Wph @ Wstep --------
__global__ __launch_bounds__(256) void k_fixed(const float* __restrict__ emb,
                                               const float* __restrict__ Wf,
                                               const float* __restrict__ Wstep,
                                               const float* __restrict__ Wph,
                                               float* __restrict__ fixedc,
                                               float* __restrict__ q0) {
  const int b = blockIdx.x;
  __shared__ float s_part[2][DD];
  __shared__ float s_ge[DD];
  const int tid = threadIdx.x;
  const int d = tid & 127, c = tid >> 7;
  const float* e = emb + (size_t)b * NN * DD;
  float acc = 0.f;
  for (int n = c * 256; n < c * 256 + 256; ++n) acc += e[(size_t)n * DD + d];
  s_part[c][d] = acc;
  __syncthreads();
  if (tid < DD) s_ge[tid] = (s_part[0][tid] + s_part[1][tid]) * (1.0f / 512.0f);
  __syncthreads();
  if (tid < DD) {
    float a = 0.f;
    for (int k = 0; k < DD; ++k) a += s_ge[k] * Wf[k * DD + tid];
    fixedc[b * DD + tid] = a;
    float pq = 0.f;
    for (int k = 0; k < 2 * DD; ++k) pq += Wph[k] * Wstep[k * DD + tid];
    q0[b * DD + tid] = a + pq;
  }
}

// ---- proj = emb @ W_node_proj : [B*N,128] x [128,384] -----------------------
__global__ __launch_bounds__(384) void k_proj(const float* __restrict__ emb,
                                              const float* __restrict__ Wp,
                                              float* __restrict__ proj) {
  const size_t row0 = (size_t)blockIdx.x * 32;
  __shared__ float s_A[32][DD];
  const int tid = threadIdx.x;  // 384
  for (int t = tid; t < 32 * DD; t += 384)
    s_A[t >> 7][t & 127] = emb[row0 * DD + t];
  __syncthreads();
  float acc[32];
#pragma unroll
  for (int r = 0; r < 32; ++r) acc[r] = 0.f;
  const int c = tid;
  for (int k = 0; k < DD; ++k) {
    float w = Wp[k * D3 + c];
#pragma unroll
    for (int r = 0; r < 32; ++r) acc[r] += s_A[r][k] * w;
  }
  for (int r = 0; r < 32; ++r) proj[(row0 + r) * D3 + c] = acc[r];
}

// ---- k_lp: in-place logit_K <- Wout @ logit_K per row -----------------------
__global__ __launch_bounds__(128) void k_lp(float* __restrict__ proj,
                                            const float* __restrict__ Wout) {
  const size_t row0 = (size_t)blockIdx.x * 32;
  __shared__ float s_L[32][DD];
  const int tid = threadIdx.x;  // 128
  for (int rr = 0; rr < 32; ++rr)
    s_L[rr][tid] = proj[(row0 + rr) * D3 + 2 * DD + tid];
  __syncthreads();
  float acc[32];
#pragma unroll
  for (int r = 0; r < 32; ++r) acc[r] = 0.f;
  for (int d = 0; d < DD; ++d) {
    const float w = Wout[tid * DD + d];
#pragma unroll
    for (int r = 0; r < 32; ++r) acc[r] += w * s_L[r][d];
  }
  for (int r = 0; r < 32; ++r)
    proj[(row0 + r) * D3 + 2 * DD + tid] = acc[r];
}

// ---- E12 = emb @ Wstep; E1 half gets +fixedc folded in ----------------------
__global__ __launch_bounds__(256) void k_ectx(const float* __restrict__ emb,
                                              const float* __restrict__ Wstep,
                                              const float* __restrict__ fixedc,
                                              float* __restrict__ E12) {
  const size_t row0 = (size_t)blockIdx.x * 32;
  __shared__ float s_A[32][DD];
  const int tid = threadIdx.x;  // 256
  for (int t = tid; t < 32 * DD; t += 256)
    s_A[t >> 7][t & 127] = emb[row0 * DD + t];
  __syncthreads();
  float acc[32];
#pragma unroll
  for (int r = 0; r < 32; ++r) acc[r] = 0.f;
  const int c = tid;
  const int b = (int)(row0 >> 9);  // 512 rows per batch
  const float* wp = (c < DD) ? (Wstep + c) : (Wstep + DD * DD + (c - DD));
  for (int k = 0; k < DD; ++k) {
    float w = wp[(size_t)k * DD];
#pragma unroll
    for (int r = 0; r < 32; ++r) acc[r] += s_A[r][k] * w;
  }
  const float fc = (c < DD) ? fixedc[b * DD + c] : 0.f;
  for (int r = 0; r < 32; ++r) E12[(row0 + r) * 256 + c] = acc[r] + fc;
}

#define DOT16(q, F)                                                           \
  (q[0] * F[0].x + q[1] * F[0].y + q[2] * F[0].z + q[3] * F[0].w +            \
   q[4] * F[1].x + q[5] * F[1].y + q[6] * F[1].z + q[7] * F[1].w +            \
   q[8] * F[2].x + q[9] * F[2].y + q[10] * F[2].z + q[11] * F[2].w +          \
   q[12] * F[3].x + q[13] * F[3].y + q[14] * F[3].z + q[15] * F[3].w)

__device__ __forceinline__ int ld_acq_i(int* p) {
  return __hip_atomic_load(p, __ATOMIC_ACQUIRE, __HIP_MEMORY_SCOPE_AGENT);
}
__device__ __forceinline__ void st_rel_i(int* p, int v) {
  __hip_atomic_store(p, v, __ATOMIC_RELEASE, __HIP_MEMORY_SCOPE_AGENT);
}
__device__ __forceinline__ float ld_f(float* p) {
  return __hip_atomic_load(p, __ATOMIC_RELAXED, __HIP_MEMORY_SCOPE_AGENT);
}
__device__ __forceinline__ void st_f(float* p, float v) {
  __hip_atomic_store(p, v, __ATOMIC_RELAXED, __HIP_MEMORY_SCOPE_AGENT);
}
__device__ __forceinline__ int ld_i(int* p) {
  return __hip_atomic_load(p, __ATOMIC_RELAXED, __HIP_MEMORY_SCOPE_AGENT);
}
__device__ __forceinline__ void st_i(int* p, int v) {
  __hip_atomic_store(p, v, __ATOMIC_RELAXED, __HIP_MEMORY_SCOPE_AGENT);
}

// ---- persistent greedy decode: TWO blocks per batch (256 blocks, all CUs) ---
// Interleaved position ownership (p&1 == half): work stays balanced as M
// shrinks, and the 128KB LDS L' cache covers ALL owned positions -> L' global
// phase eliminated. Per-step exchange: softmax partials (136 f) + argmax/LSE
// triple (4 f) via agent-scope atomics + monotonic seq flags. Pair on same
// XCD via partner = blockIdx^8 (round-robin heuristic; perf only). Both
// blocks run identical state updates (deterministic). Co-residency: 1
// block/CU (LDS-bound) x 256 = all resident; spin-wait safe.
__global__ __launch_bounds__(1024, 1) void k_decode(
    const float* __restrict__ emb, const float* __restrict__ proj,
    const float* __restrict__ fixedc, const float* __restrict__ q0,
    const float* __restrict__ E12, const float* __restrict__ Wstep,
    const float* __restrict__ Wph, const int useE, float* __restrict__ out,
    float* __restrict__ comm, int* __restrict__ flags) {
  const int x = blockIdx.x;
  const int half = (x >> 3) & 1;
  const int b = (x & 7) | ((x >> 4) << 3);
  const int tid = threadIdx.x;
  const int lane = tid & 63;
  const int wave = tid >> 6;
  const int h = tid & 7, rr = tid >> 3;  // head, row-group in [0,128)

  float* bc = comm + (size_t)b * COMM_STRIDE;
  float* mynd = bc + half * 144;
  float* pnd = bc + (1 - half) * 144;
  float* mytri = bc + 288 + half * 8;
  float* ptri = bc + 288 + (1 - half) * 8;
  int* myflag = flags + b * 2 + half;
  int* pflag = flags + b * 2 + (1 - half);

  __shared__ float4 s_Lpf[2][4][1024];  // 128 KB: L' for all owned positions
  __shared__ int s_idx[NN];
  __shared__ int s_pos[NN];
  __shared__ unsigned char s_visited[NN];
  __shared__ float s_hacc[16][8][17];
  __shared__ float s_numden[136];
  __shared__ float s_heads[DD];
  __shared__ float s_rm[16];
  __shared__ int s_ri[16];
  __shared__ float s_es[16];
  __shared__ float s_q[DD];        // fallback path only
  __shared__ float s_ctx[2 * DD];  // fallback path only
  __shared__ int s_first, s_prev, s_M, s_swap;
  __shared__ float s_ll, s_lzv;

  const float inv_sqrt_d = 0.08838834764831845f;  // 1/sqrt(128)
  const size_t eb = (size_t)b * NN * DD;
  const size_t e2 = (size_t)b * NN * 256;
  const float* projb = proj + (size_t)b * NN * D3;
  float* outp = out + (size_t)b * NN * NN;
  const size_t PI_OFF = (size_t)BATCH * NN * NN;
  const size_t LL_OFF = PI_OFF + (size_t)BATCH * NN;

  if (tid < NN) {
    s_idx[tid] = tid;
    s_pos[tid] = tid;
    s_visited[tid] = 0;
  }
  if (tid == 0) { s_first = 0; s_prev = 0; s_ll = 0.f; s_M = NN; }
  // init L' cache: owned position p = 2*(rr+128k)+half; row == p at init
#pragma unroll
  for (int k = 0; k < 2; ++k) {
    const int p = 2 * (rr + 128 * k) + half;
    const float4* lp =
        (const float4*)(projb + (size_t)p * D3 + 2 * DD + h * 16);
    s_Lpf[k][0][tid] = lp[0];
    s_Lpf[k][1][tid] = lp[1];
    s_Lpf[k][2][tid] = lp[2];
    s_Lpf[k][3][tid] = lp[3];
  }
  __syncthreads();

  for (int i = 0; i < NN; ++i) {
    const int M = s_M;
    const int first = s_first, prev = s_prev;

    // ---- qf: per-thread head fragment of q (E1' includes fixedc) -----------
    float qf[16];
    if (useE) {
      if (i == 0) {
#pragma unroll
        for (int d = 0; d < 4; ++d) {
          const float4 v = *(const float4*)(q0 + b * DD + h * 16 + d * 4);
          qf[d * 4 + 0] = v.x; qf[d * 4 + 1] = v.y;
          qf[d * 4 + 2] = v.z; qf[d * 4 + 3] = v.w;
        }
      } else {
        const float* e1p = E12 + e2 + (size_t)first * 256 + h * 16;
        const float* e2p = E12 + e2 + (size_t)prev * 256 + DD + h * 16;
#pragma unroll
        for (int d = 0; d < 4; ++d) {
          const float4 a = *(const float4*)(e1p + d * 4);
          const float4 c = *(const float4*)(e2p + d * 4);
          qf[d * 4 + 0] = a.x + c.x;
          qf[d * 4 + 1] = a.y + c.y;
          qf[d * 4 + 2] = a.z + c.z;
          qf[d * 4 + 3] = a.w + c.w;
        }
      }
    } else {
      if (tid < 2 * DD) {
        float v;
        if (i == 0)
          v = Wph[tid];
        else
          v = (tid < DD) ? emb[eb + (size_t)first * DD + tid]
                         : emb[eb + (size_t)prev * DD + (tid - DD)];
        s_ctx[tid] = v;
      }
      __syncthreads();
      if (tid < DD) {
        float a = fixedc[b * DD + tid];
        for (int k = 0; k < 2 * DD; ++k) a += s_ctx[k] * Wstep[k * DD + tid];
        s_q[tid] = a;
      }
      __syncthreads();
#pragma unroll
      for (int d = 0; d < 16; ++d) qf[d] = s_q[h * 16 + d];
    }

    // ---- owned slots (position parity == half) -----------------------------
    const int j0 = 2 * rr + half;
    const int j1 = 2 * (rr + 128) + half;
    const bool act0 = (j0 < M), act1 = (j1 < M);
    const int nj0 = s_idx[j0], nj1 = s_idx[j1];

    // ---- fused K->p->V load-and-consume (no max shift, r9-proven) ----------
    float s_l = 0.f;
    float acc[16];
#pragma unroll
    for (int d = 0; d < 16; ++d) acc[d] = 0.f;
#define KV_SLOT(ACT, NJ)                                                      \
    if (ACT) {                                                                \
      const float* rp = projb + (size_t)(NJ)*D3 + h * 16;                     \
      const float4* kp = (const float4*)rp;                                   \
      float4 k0 = kp[0], k1 = kp[1], k2 = kp[2], k3 = kp[3];                  \
      float a = qf[0] * k0.x + qf[1] * k0.y + qf[2] * k0.z + qf[3] * k0.w +   \
                qf[4] * k1.x + qf[5] * k1.y + qf[6] * k1.z + qf[7] * k1.w +   \
                qf[8] * k2.x + qf[9] * k2.y + qf[10] * k2.z + qf[11] * k2.w + \
                qf[12] * k3.x + qf[13] * k3.y + qf[14] * k3.z +               \
                qf[15] * k3.w;                                                \
      const float p = expf(a * 0.25f);                                        \
      s_l += p;                                                               \
      const float4* vp = (const float4*)(rp + DD);                            \
      float4 v0 = vp[0], v1 = vp[1], v2 = vp[2], v3 = vp[3];                  \
      acc[0] += p * v0.x;  acc[1] += p * v0.y;                                \
      acc[2] += p * v0.z;  acc[3] += p * v0.w;                                \
      acc[4] += p * v1.x;  acc[5] += p * v1.y;                                \
      acc[6] += p * v1.z;  acc[7] += p * v1.w;                                \
      acc[8] += p * v2.x;  acc[9] += p * v2.y;                                \
      acc[10] += p * v2.z; acc[11] += p * v2.w;                               \
      acc[12] += p * v3.x; acc[13] += p * v3.y;                               \
      acc[14] += p * v3.z; acc[15] += p * v3.w;                               \
    }
    KV_SLOT(act0, nj0);
    KV_SLOT(act1, nj1);
#undef KV_SLOT

    // recursive-halving reduce of acc16 over the 8 lanes sharing head h
    {
      const bool k1 = (lane & 8) == 0;
#pragma unroll
      for (int d = 0; d < 8; ++d) {
        const float send = k1 ? acc[d + 8] : acc[d];
        const float got = __shfl_xor(send, 8);
        acc[d] = (k1 ? acc[d] : acc[d + 8]) + got;
      }
      const bool k2 = (lane & 16) == 0;
#pragma unroll
      for (int d = 0; d < 4; ++d) {
        const float send = k2 ? acc[d + 4] : acc[d];
        const float got = __shfl_xor(send, 16);
        acc[d] = (k2 ? acc[d] : acc[d + 4]) + got;
      }
      const bool k3 = (lane & 32) == 0;
#pragma unroll
      for (int d = 0; d < 2; ++d) {
        const float send = k3 ? acc[d + 2] : acc[d];
        const float got = __shfl_xor(send, 32);
        acc[d] = (k3 ? acc[d] : acc[d + 2]) + got;
      }
    }
    s_l += __shfl_xor(s_l, 8);
    s_l += __shfl_xor(s_l, 16);
    s_l += __shfl_xor(s_l, 32);
    {
      const int dim0 = ((lane & 8) ? 8 : 0) | ((lane & 16) ? 4 : 0) |
                       ((lane & 32) ? 2 : 0);
      s_hacc[wave][h][dim0] = acc[0];
      s_hacc[wave][h][dim0 + 1] = acc[1];
      if (lane < 8) s_hacc[wave][lane][16] = s_l;
    }
    __syncthreads();  // B1: s_hacc ready

    // ---- block partials -> comm buffer -------------------------------------
    if (tid < 128) {
      const int hh = tid >> 4, dh = tid & 15;
      float num = 0.f;
#pragma unroll
      for (int w = 0; w < 16; ++w) num += s_hacc[w][hh][dh];
      s_numden[tid] = num;
      st_f(mynd + tid, num);
      __threadfence();
    } else if (tid < 136) {
      const int hh = tid - 128;
      float den = 0.f;
#pragma unroll
      for (int w = 0; w < 16; ++w) den += s_hacc[w][hh][16];
      s_numden[tid] = den;
      st_f(mynd + tid, den);
      __threadfence();
    }
    __syncthreads();  // B2: partials stored + fenced
    if (tid == 0) {
      st_rel_i(myflag, 2 * i + 1);
      while (ld_acq_i(pflag) < 2 * i + 1) __builtin_amdgcn_s_sleep(1);
    }
    __syncthreads();  // B3: partner partials visible

    // ---- heads = (num + pnum) / (den + pden) -------------------------------
    if (tid < 128) {
      const float pn = ld_f(pnd + tid);
      const float pd = ld_f(pnd + 128 + (tid >> 4));
      s_heads[tid] = (s_numden[tid] + pn) / (s_numden[128 + (tid >> 4)] + pd);
    }
    __syncthreads();  // B4: s_heads ready

    // ---- logits from LDS L' cache (full coverage of owned positions) -------
    float gf[16];
#pragma unroll
    for (int d = 0; d < 16; ++d) gf[d] = s_heads[h * 16 + d];
    float aa0 = 0.f, aa1 = 0.f;
    if (act0) {
      float4 LA[4];
      LA[0] = s_Lpf[0][0][tid]; LA[1] = s_Lpf[0][1][tid];
      LA[2] = s_Lpf[0][2][tid]; LA[3] = s_Lpf[0][3][tid];
      aa0 = DOT16(gf, LA);
    }
    if (act1) {
      float4 LA[4];
      LA[0] = s_Lpf[1][0][tid]; LA[1] = s_Lpf[1][1][tid];
      LA[2] = s_Lpf[1][2][tid]; LA[3] = s_Lpf[1][3][tid];
      aa1 = DOT16(gf, LA);
    }
#pragma unroll
    for (int off = 1; off <= 4; off <<= 1) {
      aa0 += __shfl_xor(aa0, off);
      aa1 += __shfl_xor(aa1, off);
    }
    const int visn = (tid < NN) ? (int)s_visited[tid] : 0;  // pre-update snap
    float av = NEGINF;
    int ai = 0x7FFFFFFF;
    float asum = 0.f;
    float lgr0 = 0.f, lgr1 = 0.f;
    if (h == 0) {
      if (act0) {
        lgr0 = 10.0f * tanhf(aa0 * inv_sqrt_d);
        asum += expf(lgr0);
        if (lgr0 > av || (lgr0 == av && nj0 < ai)) { av = lgr0; ai = nj0; }
      }
      if (act1) {
        lgr1 = 10.0f * tanhf(aa1 * inv_sqrt_d);
        asum += expf(lgr1);
        if (lgr1 > av || (lgr1 == av && nj1 < ai)) { av = lgr1; ai = nj1; }
      }
    }
#pragma unroll
    for (int off = 1; off <= 32; off <<= 1) {
      const float ov = __shfl_xor(av, off);
      const int oi = __shfl_xor(ai, off);
      asum += __shfl_xor(asum, off);
      if (ov > av || (ov == av && oi < ai)) { av = ov; ai = oi; }
    }
    if (lane == 0) { s_rm[wave] = av; s_ri[wave] = ai; s_es[wave] = asum; }
    __syncthreads();  // B5: wave triples ready

    // ---- wave0: block triple -> exchange -> selection + state --------------
    if (wave == 0) {
      float cv = (lane < 16) ? s_rm[lane] : NEGINF;
      int ci = (lane < 16) ? s_ri[lane] : 0x7FFFFFFF;
      float cs = (lane < 16) ? s_es[lane] : 0.f;
#pragma unroll
      for (int off = 1; off <= 8; off <<= 1) {
        const float ov = __shfl_xor(cv, off);
        const int oi = __shfl_xor(ci, off);
        cs += __shfl_xor(cs, off);
        if (ov > cv || (ov == cv && oi < ci)) { cv = ov; ci = oi; }
      }
      if (lane == 0) {
        st_f(mytri + 0, cv);
        st_f(mytri + 1, cs);
        st_i((int*)(mytri + 2), ci);
        st_rel_i(myflag, 2 * i + 2);  // release covers this thread's stores
        while (ld_acq_i(pflag) < 2 * i + 2) __builtin_amdgcn_s_sleep(1);
        const float ov = ld_f(ptri + 0);
        const float os = ld_f(ptri + 1);
        const int oi = ld_i((int*)(ptri + 2));
        float bv = cv;
        int bi = ci;
        float bs = cs + os;
        if (ov > bv || (ov == bv && oi < bi)) { bv = ov; bi = oi; }
        const float lzv = logf(bs);
        const int sel = bi;
        s_lzv = lzv;
        s_ll += bv - lzv;  // bv == logits[sel]
        s_visited[sel] = 1;
        if (i == 0) s_first = sel;
        s_prev = sel;
        if (half == 0) out[PI_OFF + (size_t)b * NN + i] = (float)sel;
        const int p = s_pos[sel];
        const int last = s_idx[M - 1];
        s_idx[p] = last;
        s_pos[last] = p;
        s_idx[M - 1] = sel;
        s_pos[sel] = M - 1;
        s_M = M - 1;
        s_swap = p;
      }
    }
    __syncthreads();  // B6: state + lz visible

    // ---- refresh the one changed owned cache position ----------------------
    {
      const int sp = s_swap;
      if ((sp & 1) == half && sp < M - 1) {
        const int q = (sp - half) >> 1;
        if ((tid >> 3) == (q & 127)) {
          const int k = q >> 7;
          const int nr = s_idx[sp];
          const float4* lp =
              (const float4*)(projb + (size_t)nr * D3 + 2 * DD + h * 16);
          s_Lpf[k][0][tid] = lp[0];
          s_Lpf[k][1][tid] = lp[1];
          s_Lpf[k][2][tid] = lp[2];
          s_Lpf[k][3][tid] = lp[3];
        }
      }
    }
    // ---- log_p writes: owned unvisited cols + visited cols by col parity ---
    const float lz = s_lzv;
    if (h == 0) {
      if (act0) outp[(size_t)i * NN + nj0] = lgr0 - lz;
      if (act1) outp[(size_t)i * NN + nj1] = lgr1 - lz;
    }
    if (tid < NN && visn && ((tid & 1) == half))
      outp[(size_t)i * NN + tid] = NEGV - lz;
    __syncthreads();  // B7: protect state/LDS for next step
  }
  if (tid == 0 && half == 0) out[LL_OFF + b] = s_ll;
}

extern "C" void kernel_launch(void* const* d_in, const int* in_sizes, int n_in,
                              void* d_out, int out_size, void* d_ws,
                              size_t ws_size, hipStream_t stream) {
  const float* emb = (const float*)d_in[0];    // [B,N,D]
  const float* Wnp = (const float*)d_in[1];    // [D,3D]
  const float* Wf = (const float*)d_in[2];     // [D,D]
  const float* Wstep = (const float*)d_in[3];  // [2D,D]
  const float* Wout = (const float*)d_in[4];   // [D,D]
  const float* Wph = (const float*)d_in[5];    // [2D]
  float* out = (float*)d_out;

  const size_t projN = (size_t)BATCH * NN * D3;
  const size_t eN = (size_t)BATCH * NN * 256;
  const size_t need_full = (COMM_F + projN + eN + 2 * (size_t)BATCH * DD) * 4;

  int* flags = (int*)d_ws;
  float* comm = (float*)d_ws + 256;
  float* proj = (float*)d_ws + COMM_F;
  float* E12 = proj + projN;
  const int useE = (ws_size >= need_full) ? 1 : 0;
  float* fixedc = useE ? (E12 + eN) : (proj + projN);
  float* q0 = fixedc + (size_t)BATCH * DD;

  hipMemsetAsync(flags, 0, 256 * sizeof(int), stream);  // reset seq flags
  k_fixed<<<BATCH, 256, 0, stream>>>(emb, Wf, Wstep, Wph, fixedc, q0);
  k_proj<<<(BATCH * NN) / 32, 384, 0, stream>>>(emb, Wnp, proj);
  k_lp<<<(BATCH * NN) / 32, 128, 0, stream>>>(proj, Wout);
  if (useE)
    k_ectx<<<(BATCH * NN) / 32, 256, 0, stream>>>(emb, Wstep, fixedc, E12);
  k_decode<<<2 * BATCH, 1024, 0, stream>>>(emb, proj, fixedc, q0,
                                           useE ? E12 : nullptr, Wstep, Wph,
                                           useE, out, comm, flags);
}

// Round 16
// 5801.200 us; speedup vs baseline: 3.5856x; 3.5856x over previous
//
#include <hip/hip_runtime.h>
#include <hip/hip_bf16.h>
#include <math.h>

#define BATCH 128
#define NN 512
#define DD 128
#define D3 384
#define NEGV (-1.0e9f)
#define NEGINF (-1.0e30f)

// ---- k_fixed: graph mean -> fixed ctx; also q0 = fixed + Wph @ Wstep --------
__global__ __launch_bounds__(256) void k_fixed(const float* __restrict__ emb,
                                               const float* __restrict__ Wf,
                                               const float* __restrict__ Wstep,
                                               const float* __restrict__ Wph,
                                               float* __restrict__ fixedc,
                                               float* __restrict__ q0) {
  const int b = blockIdx.x;
  __shared__ float s_part[2][DD];
  __shared__ float s_ge[DD];
  const int tid = threadIdx.x;
  const int d = tid & 127, c = tid >> 7;
  const float* e = emb + (size_t)b * NN * DD;
  float acc = 0.f;
  for (int n = c * 256; n < c * 256 + 256; ++n) acc += e[(size_t)n * DD + d];
  s_part[c][d] = acc;
  __syncthreads();
  if (tid < DD) s_ge[tid] = (s_part[0][tid] + s_part[1][tid]) * (1.0f / 512.0f);
  __syncthreads();
  if (tid < DD) {
    float a = 0.f;
    for (int k = 0; k < DD; ++k) a += s_ge[k] * Wf[k * DD + tid];
    fixedc[b * DD + tid] = a;
    float pq = 0.f;
    for (int k = 0; k < 2 * DD; ++k) pq += Wph[k] * Wstep[k * DD + tid];
    q0[b * DD + tid] = a + pq;
  }
}

// ---- proj = emb @ W_node_proj : [B*N,128] x [128,384] -----------------------
__global__ __launch_bounds__(384) void k_proj(const float* __restrict__ emb,
                                              const float* __restrict__ Wp,
                                              float* __restrict__ proj) {
  const size_t row0 = (size_t)blockIdx.x * 32;
  __shared__ float s_A[32][DD];
  const int tid = threadIdx.x;  // 384
  for (int t = tid; t < 32 * DD; t += 384)
    s_A[t >> 7][t & 127] = emb[row0 * DD + t];
  __syncthreads();
  float acc[32];
#pragma unroll
  for (int r = 0; r < 32; ++r) acc[r] = 0.f;
  const int c = tid;
  for (int k = 0; k < DD; ++k) {
    float w = Wp[k * D3 + c];
#pragma unroll
    for (int r = 0; r < 32; ++r) acc[r] += s_A[r][k] * w;
  }
  for (int r = 0; r < 32; ++r) proj[(row0 + r) * D3 + c] = acc[r];
}

// ---- k_lp: in-place logit_K <- Wout @ logit_K per row -----------------------
__global__ __launch_bounds__(128) void k_lp(float* __restrict__ proj,
                                            const float* __restrict__ Wout) {
  const size_t row0 = (size_t)blockIdx.x * 32;
  __shared__ float s_L[32][DD];
  const int tid = threadIdx.x;  // 128
  for (int rr = 0; rr < 32; ++rr)
    s_L[rr][tid] = proj[(row0 + rr) * D3 + 2 * DD + tid];
  __syncthreads();
  float acc[32];
#pragma unroll
  for (int r = 0; r < 32; ++r) acc[r] = 0.f;
  for (int d = 0; d < DD; ++d) {
    const float w = Wout[tid * DD + d];
#pragma unroll
    for (int r = 0; r < 32; ++r) acc[r] += w * s_L[r][d];
  }
  for (int r = 0; r < 32; ++r)
    proj[(row0 + r) * D3 + 2 * DD + tid] = acc[r];
}

// ---- E12 = emb @ Wstep; E1 half gets +fixedc folded in ----------------------
__global__ __launch_bounds__(256) void k_ectx(const float* __restrict__ emb,
                                              const float* __restrict__ Wstep,
                                              const float* __restrict__ fixedc,
                                              float* __restrict__ E12) {
  const size_t row0 = (size_t)blockIdx.x * 32;
  __shared__ float s_A[32][DD];
  const int tid = threadIdx.x;  // 256
  for (int t = tid; t < 32 * DD; t += 256)
    s_A[t >> 7][t & 127] = emb[row0 * DD + t];
  __syncthreads();
  float acc[32];
#pragma unroll
  for (int r = 0; r < 32; ++r) acc[r] = 0.f;
  const int c = tid;
  const int b = (int)(row0 >> 9);  // 512 rows per batch
  const float* wp = (c < DD) ? (Wstep + c) : (Wstep + DD * DD + (c - DD));
  for (int k = 0; k < DD; ++k) {
    float w = wp[(size_t)k * DD];
#pragma unroll
    for (int r = 0; r < 32; ++r) acc[r] += s_A[r][k] * w;
  }
  const float fc = (c < DD) ? fixedc[b * DD + c] : 0.f;
  for (int r = 0; r < 32; ++r) E12[(row0 + r) * 256 + c] = acc[r] + fc;
}

#define DOT16(q, F)                                                           \
  (q[0] * F[0].x + q[1] * F[0].y + q[2] * F[0].z + q[3] * F[0].w +            \
   q[4] * F[1].x + q[5] * F[1].y + q[6] * F[1].z + q[7] * F[1].w +            \
   q[8] * F[2].x + q[9] * F[2].y + q[10] * F[2].z + q[11] * F[2].w +          \
   q[12] * F[3].x + q[13] * F[3].y + q[14] * F[3].z + q[15] * F[3].w)

#define L_LOAD(njx, Lr)                                                       \
  {                                                                           \
    const float4* lp_ =                                                       \
        (const float4*)(projb + (size_t)(njx)*D3 + 2 * DD + h * 16);          \
    Lr[0] = lp_[0]; Lr[1] = lp_[1]; Lr[2] = lp_[2]; Lr[3] = lp_[3];           \
  }

#define L_CONSUME(Lr, njx)                                                    \
  {                                                                           \
    float a_ = DOT16(gf, Lr);                                                 \
    a_ += __shfl_xor(a_, 1);                                                  \
    a_ += __shfl_xor(a_, 2);                                                  \
    a_ += __shfl_xor(a_, 4);                                                  \
    if (h == 0) {                                                             \
      const float lg_ = 10.0f * tanhf(a_ * inv_sqrt_d);                       \
      s_logits[njx] = lg_;                                                    \
      asum += expf(lg_);                                                      \
      if (lg_ > av || (lg_ == av && (njx) < ai)) { av = lg_; ai = (njx); }    \
    }                                                                         \
  }

// ---- persistent greedy decode: one block per batch --------------------------
// L' (=Wout@logit_K) for compacted positions 0..255 lives persistently in LDS
// (128 KB): init once (position==row), then exactly one position changes per
// step (the swap) -> 8 threads refresh one 512B row, hidden under next step's
// phase-1. Phase-3 slot-0/1 reads become LDS reads (no LLC latency).
__global__ __launch_bounds__(1024, 1) void k_decode(
    const float* __restrict__ emb, const float* __restrict__ proj,
    const float* __restrict__ fixedc, const float* __restrict__ q0,
    const float* __restrict__ E12, const float* __restrict__ Wstep,
    const float* __restrict__ Wph, const int useE, float* __restrict__ out) {
  const int b = blockIdx.x;
  const int tid = threadIdx.x;
  const int lane = tid & 63;
  const int wave = tid >> 6;
  const int h = tid & 7, r = tid >> 3;  // head, row-group

  __shared__ float4 s_Lpf[2][4][16][64];  // 128 KB persistent L' cache
  __shared__ int s_idx[NN];
  __shared__ int s_pos[NN];
  __shared__ unsigned char s_visited[NN];
  __shared__ float s_hacc[16][8][17];  // per-wave per-head acc16 + sum
  __shared__ float s_heads[DD];
  __shared__ float s_logits[NN];
  __shared__ float s_rm[16];
  __shared__ int s_ri[16];
  __shared__ float s_es[16];
  __shared__ float s_q[DD];        // fallback path only
  __shared__ float s_ctx[2 * DD];  // fallback path only
  __shared__ int s_first, s_prev, s_M, s_swap;
  __shared__ float s_ll;

  const float inv_sqrt_d = 0.08838834764831845f;  // 1/sqrt(128)
  const size_t eb = (size_t)b * NN * DD;
  const size_t e2 = (size_t)b * NN * 256;
  const float* projb = proj + (size_t)b * NN * D3;
  float* outp = out + (size_t)b * NN * NN;
  const size_t PI_OFF = (size_t)BATCH * NN * NN;
  const size_t LL_OFF = PI_OFF + (size_t)BATCH * NN;

  if (tid < NN) {
    s_idx[tid] = tid;
    s_pos[tid] = tid;
    s_visited[tid] = 0;
  }
  if (tid == 0) { s_first = 0; s_prev = 0; s_ll = 0.f; s_M = NN; }
  // init persistent L' cache: positions 0..255 == rows r, r+128 (identity)
#pragma unroll
  for (int s = 0; s < 2; ++s) {
    const float4* lp =
        (const float4*)(projb + (size_t)(r + s * 128) * D3 + 2 * DD + h * 16);
    s_Lpf[s][0][wave][lane] = lp[0];
    s_Lpf[s][1][wave][lane] = lp[1];
    s_Lpf[s][2][wave][lane] = lp[2];
    s_Lpf[s][3][wave][lane] = lp[3];
  }
  __syncthreads();

  for (int i = 0; i < NN; ++i) {
    const int M = s_M;
    const int first = s_first, prev = s_prev;

    // ---- qf: per-thread head fragment of q (E1' includes fixedc) -----------
    float qf[16];
    if (useE) {
      if (i == 0) {
#pragma unroll
        for (int d = 0; d < 4; ++d) {
          const float4 v = *(const float4*)(q0 + b * DD + h * 16 + d * 4);
          qf[d * 4 + 0] = v.x; qf[d * 4 + 1] = v.y;
          qf[d * 4 + 2] = v.z; qf[d * 4 + 3] = v.w;
        }
      } else {
        const float* e1p = E12 + e2 + (size_t)first * 256 + h * 16;
        const float* e2p = E12 + e2 + (size_t)prev * 256 + DD + h * 16;
#pragma unroll
        for (int d = 0; d < 4; ++d) {
          const float4 a = *(const float4*)(e1p + d * 4);
          const float4 c = *(const float4*)(e2p + d * 4);
          qf[d * 4 + 0] = a.x + c.x;
          qf[d * 4 + 1] = a.y + c.y;
          qf[d * 4 + 2] = a.z + c.z;
          qf[d * 4 + 3] = a.w + c.w;
        }
      }
    } else {
      if (tid < 2 * DD) {
        float v;
        if (i == 0)
          v = Wph[tid];
        else
          v = (tid < DD) ? emb[eb + (size_t)first * DD + tid]
                         : emb[eb + (size_t)prev * DD + (tid - DD)];
        s_ctx[tid] = v;
      }
      __syncthreads();
      if (tid < DD) {
        float a = fixedc[b * DD + tid];
        for (int k = 0; k < 2 * DD; ++k) a += s_ctx[k] * Wstep[k * DD + tid];
        s_q[tid] = a;
      }
      __syncthreads();
#pragma unroll
      for (int d = 0; d < 16; ++d) qf[d] = s_q[h * 16 + d];
    }

    // ---- [top,B1): fused K->p->V load-and-consume (no max shift, r9) -------
    bool act[4];
    int nj[4];
#pragma unroll
    for (int k = 0; k < 4; ++k) {
      const int j = r + k * 128;
      act[k] = (j < M);
      nj[k] = s_idx[j];
    }
    float s_l = 0.f;
    float acc[16];
#pragma unroll
    for (int d = 0; d < 16; ++d) acc[d] = 0.f;
#pragma unroll
    for (int k = 0; k < 4; ++k) {
      if (act[k]) {
        const float* rp = projb + (size_t)nj[k] * D3 + h * 16;
        const float4* kp = (const float4*)rp;
        float4 k0 = kp[0], k1 = kp[1], k2 = kp[2], k3 = kp[3];
        float a = qf[0] * k0.x + qf[1] * k0.y + qf[2] * k0.z + qf[3] * k0.w +
                  qf[4] * k1.x + qf[5] * k1.y + qf[6] * k1.z + qf[7] * k1.w +
                  qf[8] * k2.x + qf[9] * k2.y + qf[10] * k2.z + qf[11] * k2.w +
                  qf[12] * k3.x + qf[13] * k3.y + qf[14] * k3.z +
                  qf[15] * k3.w;
        const float p = expf(a * 0.25f);  // 1/sqrt(16)
        s_l += p;
        const float4* vp = (const float4*)(rp + DD);
        float4 v0 = vp[0], v1 = vp[1], v2 = vp[2], v3 = vp[3];
        acc[0] += p * v0.x;  acc[1] += p * v0.y;
        acc[2] += p * v0.z;  acc[3] += p * v0.w;
        acc[4] += p * v1.x;  acc[5] += p * v1.y;
        acc[6] += p * v1.z;  acc[7] += p * v1.w;
        acc[8] += p * v2.x;  acc[9] += p * v2.y;
        acc[10] += p * v2.z; acc[11] += p * v2.w;
        acc[12] += p * v3.x; acc[13] += p * v3.y;
        acc[14] += p * v3.z; acc[15] += p * v3.w;
      }
    }
    // recursive-halving reduce of acc16 over the 8 lanes sharing head h
    {
      const bool k1 = (lane & 8) == 0;
#pragma unroll
      for (int d = 0; d < 8; ++d) {
        const float send = k1 ? acc[d + 8] : acc[d];
        const float got = __shfl_xor(send, 8);
        acc[d] = (k1 ? acc[d] : acc[d + 8]) + got;
      }
      const bool k2 = (lane & 16) == 0;
#pragma unroll
      for (int d = 0; d < 4; ++d) {
        const float send = k2 ? acc[d + 4] : acc[d];
        const float got = __shfl_xor(send, 16);
        acc[d] = (k2 ? acc[d] : acc[d + 4]) + got;
      }
      const bool k3 = (lane & 32) == 0;
#pragma unroll
      for (int d = 0; d < 2; ++d) {
        const float send = k3 ? acc[d + 2] : acc[d];
        const float got = __shfl_xor(send, 32);
        acc[d] = (k3 ? acc[d] : acc[d + 2]) + got;
      }
    }
    s_l += __shfl_xor(s_l, 8);
    s_l += __shfl_xor(s_l, 16);
    s_l += __shfl_xor(s_l, 32);
    {
      const int dim0 = ((lane & 8) ? 8 : 0) | ((lane & 16) ? 4 : 0) |
                       ((lane & 32) ? 2 : 0);
      s_hacc[wave][h][dim0] = acc[0];
      s_hacc[wave][h][dim0 + 1] = acc[1];
      if (lane < 8) s_hacc[wave][lane][16] = s_l;
    }
    if (tid >= 512) {
      const int t2 = tid - 512;
      if (s_visited[t2]) s_logits[t2] = NEGV;
    }
    __syncthreads();  // B1: s_hacc ready

    // ---- [B1,B2): heads = num/den (plain sums) -----------------------------
    if (tid < DD) {
      const int hh = tid >> 4, dh = tid & 15;
      float num = 0.f, den = 0.f;
#pragma unroll
      for (int w = 0; w < 16; ++w) {
        num += s_hacc[w][hh][dh];
        den += s_hacc[w][hh][16];
      }
      s_heads[tid] = num / den;
    }
    __syncthreads();  // B2: s_heads ready

    // ---- [B2,B3): logits: slots 0,1 from LDS cache; 2,3 serial global ------
    float gf[16];
#pragma unroll
    for (int d = 0; d < 16; ++d) gf[d] = s_heads[h * 16 + d];
    float av = NEGINF;
    int ai = 0x7FFFFFFF;
    float asum = 0.f;
    if (act[0]) {
      float4 LA[4];
      LA[0] = s_Lpf[0][0][wave][lane];
      LA[1] = s_Lpf[0][1][wave][lane];
      LA[2] = s_Lpf[0][2][wave][lane];
      LA[3] = s_Lpf[0][3][wave][lane];
      L_CONSUME(LA, nj[0]);
    }
    if (act[1]) {
      float4 LA[4];
      LA[0] = s_Lpf[1][0][wave][lane];
      LA[1] = s_Lpf[1][1][wave][lane];
      LA[2] = s_Lpf[1][2][wave][lane];
      LA[3] = s_Lpf[1][3][wave][lane];
      L_CONSUME(LA, nj[1]);
    }
    if (act[2]) {
      float4 LA[4];
      L_LOAD(nj[2], LA);
      L_CONSUME(LA, nj[2]);
    }
    if (act[3]) {
      float4 LA[4];
      L_LOAD(nj[3], LA);
      L_CONSUME(LA, nj[3]);
    }
#pragma unroll
    for (int off = 1; off <= 32; off <<= 1) {
      const float ov = __shfl_xor(av, off);
      const int oi = __shfl_xor(ai, off);
      asum += __shfl_xor(asum, off);
      if (ov > av || (ov == av && oi < ai)) { av = ov; ai = oi; }
    }
    if (lane == 0) { s_rm[wave] = av; s_ri[wave] = ai; s_es[wave] = asum; }
    __syncthreads();  // B3: s_logits + wave triples ready

    // ---- [B3,B4): all-thread combine; write log_p; tid0 state update -------
    float bv = s_rm[0];
    int bi = s_ri[0];
    float bs = s_es[0];
#pragma unroll
    for (int w2 = 1; w2 < 16; ++w2) {
      const float ov = s_rm[w2];
      const int oi = s_ri[w2];
      bs += s_es[w2];
      if (ov > bv || (ov == bv && oi < bi)) { bv = ov; bi = oi; }
    }
    const float lz = logf(bs);
    const int sel = bi;
    if (tid < NN) outp[(size_t)i * NN + tid] = s_logits[tid] - lz;
    if (tid == 0) {
      s_ll += s_logits[sel] - lz;
      s_visited[sel] = 1;
      if (i == 0) s_first = sel;
      s_prev = sel;
      out[PI_OFF + (size_t)b * NN + i] = (float)sel;
      const int p = s_pos[sel];
      const int last = s_idx[M - 1];
      s_idx[p] = last;
      s_pos[last] = p;
      s_idx[M - 1] = sel;
      s_pos[sel] = M - 1;
      s_M = M - 1;
      s_swap = p;  // position whose content changed (now holds `last`)
    }
    __syncthreads();  // B4: sel/logZ/compaction visible

    // ---- refresh the one changed cache position (hidden under next phase-1)
    {
      const int sp = s_swap;
      if (sp < 256 && r == (sp & 127)) {
        const int sl = sp >> 7;
        const int nr = s_idx[sp];
        const float4* lp =
            (const float4*)(projb + (size_t)nr * D3 + 2 * DD + h * 16);
        s_Lpf[sl][0][wave][lane] = lp[0];
        s_Lpf[sl][1][wave][lane] = lp[1];
        s_Lpf[sl][2][wave][lane] = lp[2];
        s_Lpf[sl][3][wave][lane] = lp[3];
      }
    }
  }
  if (tid == 0) out[LL_OFF + b] = s_ll;
}

extern "C" void kernel_launch(void* const* d_in, const int* in_sizes, int n_in,
                              void* d_out, int out_size, void* d_ws,
                              size_t ws_size, hipStream_t stream) {
  const float* emb = (const float*)d_in[0];    // [B,N,D]
  const float* Wnp = (const float*)d_in[1];    // [D,3D]
  const float* Wf = (const float*)d_in[2];     // [D,D]
  const float* Wstep = (const float*)d_in[3];  // [2D,D]
  const float* Wout = (const float*)d_in[4];   // [D,D]
  const float* Wph = (const float*)d_in[5];    // [2D]
  float* out = (float*)d_out;

  const size_t projN = (size_t)BATCH * NN * D3;
  const size_t eN = (size_t)BATCH * NN * 256;
  const size_t need_full = (projN + eN + 2 * (size_t)BATCH * DD) * 4;

  float* proj = (float*)d_ws;
  float* E12 = proj + projN;
  const int useE = (ws_size >= need_full) ? 1 : 0;
  float* fixedc = useE ? (E12 + eN) : (proj + projN);
  float* q0 = fixedc + (size_t)BATCH * DD;

  k_fixed<<<BATCH, 256, 0, stream>>>(emb, Wf, Wstep, Wph, fixedc, q0);
  k_proj<<<(BATCH * NN) / 32, 384, 0, stream>>>(emb, Wnp, proj);
  k_lp<<<(BATCH * NN) / 32, 128, 0, stream>>>(proj, Wout);
  if (useE) k_ectx<<<(BATCH * NN) / 32, 256, 0, stream>>>(emb, Wstep, fixedc, E12);
  k_decode<<<BATCH, 1024, 0, stream>>>(emb, proj, fixedc, q0,
                                       useE ? E12 : nullptr, Wstep, Wph, useE,
                                       out);
}